// Round 11
// baseline (174.018 us; speedup 1.0000x reference)
//
#include <hip/hip_runtime.h>
#include <hip/hip_bf16.h>

// MHA: B=8, S=1024, D=1024, H=16, DH=64.
// R22: [qkv] R13 version (measured-good, ~11us, traffic-roofline).
// [attn] = R16 (TB=64, 4 blk/CU, verified 41.4us r10) MINUS V-staging:
//   V fragments are lane-row-local (each lane reads only its own e-row), so
//   LDS buys nothing for V (Common-mistake #7 / m169: +26% from dropping
//   V-staging at S=1024). V is read directly global->reg, issued right after
//   the barrier BEFORE the K prefetch gload_lds (so the compiler's counted
//   vmcnt for V regs doesn't drain the K pipeline), consumed in PV ~400cy
//   later (covers L2 ~200cy; per-XCD V slice = 2MB, L2-resident).
//   LDS 32KB->16KB/block; 2 fewer gloads/wave/tile; shorter barrier drain.
// r10 counters: attn 41.4us, MfmaUtil 36, VALU 38.7, Occ 28.7 (occupancy
// doubled but only -1.8us => stall is staging/serialization, not wave count).

constexpr int NB = 8, NS = 1024, ND = 1024, NH = 16, NDH = 64;

typedef __bf16 bf16x8 __attribute__((ext_vector_type(8)));
typedef float f32x4 __attribute__((ext_vector_type(4)));

__device__ __forceinline__ f32x4 mfma16(bf16x8 a, bf16x8 b, f32x4 c) {
  return __builtin_amdgcn_mfma_f32_16x16x32_bf16(a, b, c, 0, 0, 0);
}

__device__ __forceinline__ float fast_exp2(float x) {
#if __has_builtin(__builtin_amdgcn_exp2f)
  return __builtin_amdgcn_exp2f(x);   // raw v_exp_f32
#else
  return __builtin_exp2f(x);
#endif
}

// RNE-ish pack (round-half-up) — used in proj where cost is negligible.
__device__ __forceinline__ unsigned pack2(float lo, float hi) {
  unsigned uh = __builtin_bit_cast(unsigned, hi) + 0x8000u;
  unsigned ul = __builtin_bit_cast(unsigned, lo) + 0x8000u;
  return __builtin_amdgcn_perm(uh, ul, 0x07060302u);
}

// Truncation pack — 1 VALU; used for P (bias cancels num/den).
__device__ __forceinline__ unsigned pack2t(float lo, float hi) {
  return __builtin_amdgcn_perm(__builtin_bit_cast(unsigned, hi),
                               __builtin_bit_cast(unsigned, lo), 0x07060302u);
}

__device__ __forceinline__ bf16x8 cvt2bf8(float4 lo, float4 hi) {
  bf16x8 r;
  r[0] = (__bf16)lo.x; r[1] = (__bf16)lo.y; r[2] = (__bf16)lo.z; r[3] = (__bf16)lo.w;
  r[4] = (__bf16)hi.x; r[5] = (__bf16)hi.y; r[6] = (__bf16)hi.z; r[7] = (__bf16)hi.w;
  return r;
}

__device__ __forceinline__ void gload16(const __hip_bfloat16* g, __hip_bfloat16* l) {
  __builtin_amdgcn_global_load_lds(
      (const __attribute__((address_space(1))) void*)g,
      (__attribute__((address_space(3))) void*)l, 16, 0, 0);
}

// ---------------- QKV projection (R13 version — measured-good) ----------
__global__ __launch_bounds__(256) void qkv_proj_kernel(
    const float* __restrict__ x,
    const float* __restrict__ Wq, const float* __restrict__ bq,
    const float* __restrict__ Wk, const float* __restrict__ bk,
    const float* __restrict__ Wv, const float* __restrict__ bv,
    __hip_bfloat16* __restrict__ Qo, __hip_bfloat16* __restrict__ Ko,
    __hip_bfloat16* __restrict__ Vt) {
  __shared__ __align__(16) __hip_bfloat16 Wlds[3][NDH][72];
  const int tid = threadIdx.x;
  const int wave = tid >> 6, lane = tid & 63;
  const int m = lane & 15, quad = lane >> 4;
  const int h = blockIdx.x & (NH - 1);
  const int sblk = blockIdx.x >> 4;

  const float* Ws[3] = {Wq + h * 4096, Wk + h * 4096, Wv + h * 4096};
#pragma unroll
  for (int mt = 0; mt < 3; mt++) {
#pragma unroll
    for (int p = 0; p < 4; p++) {
      int idx = (p * 256 + tid) * 4;
      float4 v = *(const float4*)(Ws[mt] + idx);
      uint2 w;
      w.x = pack2(v.x, v.y);
      w.y = pack2(v.z, v.w);
      *(uint2*)&Wlds[mt][idx >> 6][idx & 63] = w;
    }
  }
  __syncthreads();

  float bq4[4][4], bk4[4][4], bvv[4];
#pragma unroll
  for (int nt = 0; nt < 4; nt++) {
    float4 a = *(const float4*)(bq + h * 64 + nt * 16 + quad * 4);
    float4 c = *(const float4*)(bk + h * 64 + nt * 16 + quad * 4);
    bq4[nt][0] = a.x; bq4[nt][1] = a.y; bq4[nt][2] = a.z; bq4[nt][3] = a.w;
    bk4[nt][0] = c.x; bk4[nt][1] = c.y; bk4[nt][2] = c.z; bk4[nt][3] = c.w;
    bvv[nt] = bv[h * 64 + nt * 16 + m];
  }

  const int rowbase = sblk * 256 + wave * 64;
  bf16x8 Xf[4][2];
#pragma unroll
  for (int st = 0; st < 4; st++) {
    const float* xp = x + (size_t)(rowbase + st * 16 + m) * ND + h * NDH + quad * 8;
#pragma unroll
    for (int c = 0; c < 2; c++) {
      float4 lo = *(const float4*)(xp + c * 32);
      float4 hi = *(const float4*)(xp + c * 32 + 4);
      Xf[st][c] = cvt2bf8(lo, hi);
    }
  }

  const int b = rowbase >> 10;
  const int s0 = rowbase & 1023;
  const float qscale = 0.18033688011112042f;  // log2(e)/sqrt(64)

#pragma unroll
  for (int mt = 0; mt < 3; mt++) {
#pragma unroll
    for (int nt = 0; nt < 4; nt++) {
      bf16x8 w0 = *(const bf16x8*)&Wlds[mt][nt * 16 + m][quad * 8];
      bf16x8 w1 = *(const bf16x8*)&Wlds[mt][nt * 16 + m][32 + quad * 8];
#pragma unroll
      for (int st = 0; st < 4; st++) {
        f32x4 acc = {0.f, 0.f, 0.f, 0.f};
        if (mt < 2) {
          acc = mfma16(w0, Xf[st][0], acc);
          acc = mfma16(w1, Xf[st][1], acc);
          const int srow = s0 + st * 16 + m;
          uint2 w;
          if (mt == 0) {
            w.x = pack2((acc[0] + bq4[nt][0]) * qscale, (acc[1] + bq4[nt][1]) * qscale);
            w.y = pack2((acc[2] + bq4[nt][2]) * qscale, (acc[3] + bq4[nt][3]) * qscale);
            *(uint2*)(Qo + ((size_t)(b * NH + h) * NS + srow) * NDH +
                      nt * 16 + quad * 4) = w;
          } else {
            w.x = pack2(acc[0] + bk4[nt][0], acc[1] + bk4[nt][1]);
            w.y = pack2(acc[2] + bk4[nt][2], acc[3] + bk4[nt][3]);
            *(uint2*)(Ko + ((size_t)(b * NH + h) * NS + srow) * NDH +
                      nt * 16 + quad * 4) = w;
          }
        } else {
          acc = mfma16(Xf[st][0], w0, acc);
          acc = mfma16(Xf[st][1], w1, acc);
          uint2 w;
          w.x = pack2(acc[0] + bvv[nt], acc[1] + bvv[nt]);
          w.y = pack2(acc[2] + bvv[nt], acc[3] + bvv[nt]);
          *(uint2*)(Vt + ((size_t)(b * NH + h) * NDH + nt * 16 + m) * NS + s0 +
                    st * 16 + quad * 4) = w;
        }
      }
    }
  }
}

// ---------------- Attention (R22: TB=64, K in LDS, V direct-to-reg) --------
// Grid: 1024 blocks = 8 xcd x 16 bh x 8 qblk; block = 128 q-rows (4 waves
// x 32 rows). K tile 64x64 double-buffered: 16KB LDS. V read global->reg.
__global__ __launch_bounds__(256, 4) void attn_kernel(
    const __hip_bfloat16* __restrict__ Q,   // [B,H,S,DH] pre-scaled
    const __hip_bfloat16* __restrict__ K,   // [B,H,S,DH]
    const __hip_bfloat16* __restrict__ Vt,  // [B,H,DH,S]
    float* __restrict__ out) {              // [B,S,D]
  __shared__ __align__(16) __hip_bfloat16 Kt[2][64][64];

  const int tid = threadIdx.x;
  const int wave = tid >> 6, lane = tid & 63;
  const int m = lane & 15, quad = lane >> 4;

  const int xcd = blockIdx.x & 7;
  const int j = blockIdx.x >> 3;          // 0..127
  const int bh = xcd * 16 + (j & 15);     // same-bh blocks share an XCD (L2)
  const int qblk = j >> 4;                // 0..7
  const int qbase = qblk * 128 + wave * 32;  // 32 q-rows per wave (2 g of 16)

  const __hip_bfloat16* Qp = Q + (size_t)bh * NS * NDH;
  const __hip_bfloat16* Kp = K + (size_t)bh * NS * NDH;
  const __hip_bfloat16* Vp = Vt + (size_t)bh * NDH * NS;

  // Q as B-fragments (k32): lane holds Q[q][d = dh*32 + quad*8 + j']
  bf16x8 Bq[2][2];
#pragma unroll
  for (int g = 0; g < 2; g++)
#pragma unroll
    for (int dh = 0; dh < 2; dh++)
      Bq[g][dh] = *(const bf16x8*)(Qp + (size_t)(qbase + g * 16 + m) * NDH +
                                   dh * 32 + quad * 8);

  f32x4 accO[2][4];
  f32x4 lsum[2];
#pragma unroll
  for (int g = 0; g < 2; g++) {
    lsum[g] = (f32x4){0.f, 0.f, 0.f, 0.f};
#pragma unroll
    for (int nt = 0; nt < 4; nt++) accO[g][nt] = (f32x4){0.f, 0.f, 0.f, 0.f};
  }
  bf16x8 ones8;
#pragma unroll
  for (int i = 0; i < 8; i++) ones8[i] = (__bf16)1.0f;
  const f32x4 fzero = {0.f, 0.f, 0.f, 0.f};

  // Frag-read constants (per lane):
  const int krow = 8 * (m >> 2) + (m & 3);       // + c*32 + 4p at use site
  const int fK = (m & 3) ^ (((m >> 2) & 1) << 2);
  const int kc0 = (quad ^ fK) * 8;               // K chunk offset (elems)
  // V fragment (B-operand) base: lane reads its own e-row, no LDS, no swizzle:
  const __hip_bfloat16* vrow = Vp + (size_t)m * NS + quad * 8;  // + nt*16*NS + tb*64 + c*32

  // K staging per tile: per wave 2 lines (8 rows x 8 chunks of 16B).
  // Swizzle preserves: phys = logical ^ (r&3) ^ (((r>>3)&1)<<2).
#define STAGE(buf, tb)                                                        \
  {                                                                           \
    _Pragma("unroll") for (int l = 0; l < 2; l++) {                           \
      const int krb = wave * 16 + l * 8;                                      \
      const int csK = (lane & 7) ^ ((lane >> 3) & 3) ^ (l << 2);              \
      gload16(Kp + (size_t)((tb) * 64 + krb + (lane >> 3)) * NDH + csK * 8,   \
              &Kt[buf][krb][0]);                                              \
    }                                                                         \
  }

  STAGE(0, 0);

  for (int tb = 0; tb < 16; tb++) {
    const int cur = tb & 1;
    __syncthreads();  // own K staging drained (vmcnt 0) + block synced

    // ---- issue V loads for THIS tile first (oldest in vmcnt queue), so
    // the PV-phase wait on them does not drain the K prefetch below ----
    bf16x8 vfrag[4][2];
#pragma unroll
    for (int nt = 0; nt < 4; nt++)
#pragma unroll
      for (int c = 0; c < 2; c++)
        vfrag[nt][c] = *(const bf16x8*)(vrow + (size_t)(nt * 16) * NS +
                                        tb * 64 + c * 32);

    if (tb + 1 < 16) STAGE(cur ^ 1, tb + 1);  // K prefetch overlaps compute

    // ---- phase-split QK^T + exp: P lands in k32 A-layout ----
    bf16x8 Pa[2][2];  // [g][c]: lane holds P[q][t = c*32 + 8*quad + j]
#pragma unroll
    for (int c = 0; c < 2; c++) {
      uint4 u[2];
#pragma unroll
      for (int p = 0; p < 2; p++) {
        const __hip_bfloat16* kr = &Kt[cur][c * 32 + 4 * p + krow][0];
        bf16x8 k0 = *(const bf16x8*)(kr + kc0);
        bf16x8 k1 = *(const bf16x8*)(kr + (kc0 ^ 32));
#pragma unroll
        for (int g = 0; g < 2; g++) {
          f32x4 a = mfma16(k1, Bq[g][1], mfma16(k0, Bq[g][0], fzero));
          unsigned w0 = pack2t(fast_exp2(a[0]), fast_exp2(a[1]));
          unsigned w1 = pack2t(fast_exp2(a[2]), fast_exp2(a[3]));
          if (p == 0) { u[g].x = w0; u[g].y = w1; }
          else        { u[g].z = w0; u[g].w = w1; }
        }
      }
#pragma unroll
      for (int g = 0; g < 2; g++) Pa[g][c] = __builtin_bit_cast(bf16x8, u[g]);
    }
    // ---- pure-MFMA cluster: denom + PV (T5 retained) ----
    __builtin_amdgcn_s_setprio(1);
#pragma unroll
    for (int g = 0; g < 2; g++)
#pragma unroll
      for (int c = 0; c < 2; c++) lsum[g] = mfma16(Pa[g][c], ones8, lsum[g]);
#pragma unroll
    for (int nt = 0; nt < 4; nt++) {
#pragma unroll
      for (int c = 0; c < 2; c++) {
#pragma unroll
        for (int g = 0; g < 2; g++)
          accO[g][nt] = mfma16(Pa[g][c], vfrag[nt][c], accO[g][nt]);
      }
    }
    __builtin_amdgcn_s_setprio(0);
  }
#undef STAGE

  // ---- epilogue: O[q][e]/l[q]; q = quad*4+r, e = nt*16+m ----
  const int b = bh >> 4, h = bh & (NH - 1);
#pragma unroll
  for (int g = 0; g < 2; g++) {
#pragma unroll
    for (int r = 0; r < 4; r++) {
      float inv = 1.0f / lsum[g][r];
      int srow = qbase + g * 16 + quad * 4 + r;
      float* op = out + (size_t)(b * NS + srow) * ND + h * NDH;
#pragma unroll
      for (int nt = 0; nt < 4; nt++) op[nt * 16 + m] = accO[g][nt][r] * inv;
    }
  }
}

extern "C" void kernel_launch(void* const* d_in, const int* in_sizes, int n_in,
                              void* d_out, int out_size, void* d_ws, size_t ws_size,
                              hipStream_t stream) {
  const float* x  = (const float*)d_in[0];
  const float* Wq = (const float*)d_in[1];
  const float* bq = (const float*)d_in[2];
  const float* Wk = (const float*)d_in[3];
  const float* bk = (const float*)d_in[4];
  const float* Wv = (const float*)d_in[5];
  const float* bv = (const float*)d_in[6];
  float* out = (float*)d_out;

  const size_t elems = (size_t)NB * NH * NS * NDH;
  __hip_bfloat16* Qw = (__hip_bfloat16*)d_ws;
  __hip_bfloat16* Kw = Qw + elems;
  __hip_bfloat16* Vw = Kw + elems;

  // R13 qkv: 512 blocks, 256 rows each (measured in the 140.2 config)
  qkv_proj_kernel<<<512, 256, 0, stream>>>(x, Wq, bq, Wk, bk, Wv, bv, Qw, Kw, Vw);
  // R22 attn: 8 xcd x 16 bh x 8 qblk; 128 q-rows/block; 4 blocks/CU
  attn_kernel<<<1024, 256, 0, stream>>>(Qw, Kw, Vw, out);
}

// Round 12
// 153.388 us; speedup vs baseline: 1.1345x; 1.1345x over previous
//
#include <hip/hip_runtime.h>
#include <hip/hip_bf16.h>

// MHA: B=8, S=1024, D=1024, H=16, DH=64.
// R24: [qkv] R13 (measured-good ~11-14us). [attn] = R20 base (TB=64, 41.4us
// verified) + T15 cross-tile pipeline:
//   - PV deferred one tile: iter t computes QK+exp(tile t) AND denom+PV(t-1)
//     in ONE scheduling region -> QK-MFMA, exp-VALU, PV-MFMA independent =>
//     two-pipe overlap (the r10/r11 profile shows MfmaUtil 36 + VALU 39 with
//     both idle 60% = per-wave chain serialization).
//   - V triple-buffered (write (t+1)%3, PV reads (t-1)%3 — disjoint; K stays
//     double-buffered). Still 1 barrier/tile. LDS 40KB -> 4 blocks/CU exactly.
//   - tb-loop unrolled x2 with named PaA/PaB (no runtime-indexed regs).
//   - setprio REMOVED (null twice; would pin scheduling across the region).
// R22 lesson: V must stay LDS-staged — direct per-lane V loads stride 2KB,
// fragment into 16x64B transactions (attn 41->77us, FETCH +10MB). Reverted.

constexpr int NB = 8, NS = 1024, ND = 1024, NH = 16, NDH = 64;

typedef __bf16 bf16x8 __attribute__((ext_vector_type(8)));
typedef float f32x4 __attribute__((ext_vector_type(4)));

__device__ __forceinline__ f32x4 mfma16(bf16x8 a, bf16x8 b, f32x4 c) {
  return __builtin_amdgcn_mfma_f32_16x16x32_bf16(a, b, c, 0, 0, 0);
}

__device__ __forceinline__ float fast_exp2(float x) {
#if __has_builtin(__builtin_amdgcn_exp2f)
  return __builtin_amdgcn_exp2f(x);   // raw v_exp_f32
#else
  return __builtin_exp2f(x);
#endif
}

// RNE-ish pack (round-half-up) — used in proj where cost is negligible.
__device__ __forceinline__ unsigned pack2(float lo, float hi) {
  unsigned uh = __builtin_bit_cast(unsigned, hi) + 0x8000u;
  unsigned ul = __builtin_bit_cast(unsigned, lo) + 0x8000u;
  return __builtin_amdgcn_perm(uh, ul, 0x07060302u);
}

// Truncation pack — 1 VALU; used for P (bias cancels num/den).
__device__ __forceinline__ unsigned pack2t(float lo, float hi) {
  return __builtin_amdgcn_perm(__builtin_bit_cast(unsigned, hi),
                               __builtin_bit_cast(unsigned, lo), 0x07060302u);
}

__device__ __forceinline__ bf16x8 cvt2bf8(float4 lo, float4 hi) {
  bf16x8 r;
  r[0] = (__bf16)lo.x; r[1] = (__bf16)lo.y; r[2] = (__bf16)lo.z; r[3] = (__bf16)lo.w;
  r[4] = (__bf16)hi.x; r[5] = (__bf16)hi.y; r[6] = (__bf16)hi.z; r[7] = (__bf16)hi.w;
  return r;
}

__device__ __forceinline__ void gload16(const __hip_bfloat16* g, __hip_bfloat16* l) {
  __builtin_amdgcn_global_load_lds(
      (const __attribute__((address_space(1))) void*)g,
      (__attribute__((address_space(3))) void*)l, 16, 0, 0);
}

// ---------------- QKV projection (R13 version — measured-good) ----------
__global__ __launch_bounds__(256) void qkv_proj_kernel(
    const float* __restrict__ x,
    const float* __restrict__ Wq, const float* __restrict__ bq,
    const float* __restrict__ Wk, const float* __restrict__ bk,
    const float* __restrict__ Wv, const float* __restrict__ bv,
    __hip_bfloat16* __restrict__ Qo, __hip_bfloat16* __restrict__ Ko,
    __hip_bfloat16* __restrict__ Vt) {
  __shared__ __align__(16) __hip_bfloat16 Wlds[3][NDH][72];
  const int tid = threadIdx.x;
  const int wave = tid >> 6, lane = tid & 63;
  const int m = lane & 15, quad = lane >> 4;
  const int h = blockIdx.x & (NH - 1);
  const int sblk = blockIdx.x >> 4;

  const float* Ws[3] = {Wq + h * 4096, Wk + h * 4096, Wv + h * 4096};
#pragma unroll
  for (int mt = 0; mt < 3; mt++) {
#pragma unroll
    for (int p = 0; p < 4; p++) {
      int idx = (p * 256 + tid) * 4;
      float4 v = *(const float4*)(Ws[mt] + idx);
      uint2 w;
      w.x = pack2(v.x, v.y);
      w.y = pack2(v.z, v.w);
      *(uint2*)&Wlds[mt][idx >> 6][idx & 63] = w;
    }
  }
  __syncthreads();

  float bq4[4][4], bk4[4][4], bvv[4];
#pragma unroll
  for (int nt = 0; nt < 4; nt++) {
    float4 a = *(const float4*)(bq + h * 64 + nt * 16 + quad * 4);
    float4 c = *(const float4*)(bk + h * 64 + nt * 16 + quad * 4);
    bq4[nt][0] = a.x; bq4[nt][1] = a.y; bq4[nt][2] = a.z; bq4[nt][3] = a.w;
    bk4[nt][0] = c.x; bk4[nt][1] = c.y; bk4[nt][2] = c.z; bk4[nt][3] = c.w;
    bvv[nt] = bv[h * 64 + nt * 16 + m];
  }

  const int rowbase = sblk * 256 + wave * 64;
  bf16x8 Xf[4][2];
#pragma unroll
  for (int st = 0; st < 4; st++) {
    const float* xp = x + (size_t)(rowbase + st * 16 + m) * ND + h * NDH + quad * 8;
#pragma unroll
    for (int c = 0; c < 2; c++) {
      float4 lo = *(const float4*)(xp + c * 32);
      float4 hi = *(const float4*)(xp + c * 32 + 4);
      Xf[st][c] = cvt2bf8(lo, hi);
    }
  }

  const int b = rowbase >> 10;
  const int s0 = rowbase & 1023;
  const float qscale = 0.18033688011112042f;  // log2(e)/sqrt(64)

#pragma unroll
  for (int mt = 0; mt < 3; mt++) {
#pragma unroll
    for (int nt = 0; nt < 4; nt++) {
      bf16x8 w0 = *(const bf16x8*)&Wlds[mt][nt * 16 + m][quad * 8];
      bf16x8 w1 = *(const bf16x8*)&Wlds[mt][nt * 16 + m][32 + quad * 8];
#pragma unroll
      for (int st = 0; st < 4; st++) {
        f32x4 acc = {0.f, 0.f, 0.f, 0.f};
        if (mt < 2) {
          acc = mfma16(w0, Xf[st][0], acc);
          acc = mfma16(w1, Xf[st][1], acc);
          const int srow = s0 + st * 16 + m;
          uint2 w;
          if (mt == 0) {
            w.x = pack2((acc[0] + bq4[nt][0]) * qscale, (acc[1] + bq4[nt][1]) * qscale);
            w.y = pack2((acc[2] + bq4[nt][2]) * qscale, (acc[3] + bq4[nt][3]) * qscale);
            *(uint2*)(Qo + ((size_t)(b * NH + h) * NS + srow) * NDH +
                      nt * 16 + quad * 4) = w;
          } else {
            w.x = pack2(acc[0] + bk4[nt][0], acc[1] + bk4[nt][1]);
            w.y = pack2(acc[2] + bk4[nt][2], acc[3] + bk4[nt][3]);
            *(uint2*)(Ko + ((size_t)(b * NH + h) * NS + srow) * NDH +
                      nt * 16 + quad * 4) = w;
          }
        } else {
          acc = mfma16(Xf[st][0], w0, acc);
          acc = mfma16(Xf[st][1], w1, acc);
          uint2 w;
          w.x = pack2(acc[0] + bvv[nt], acc[1] + bvv[nt]);
          w.y = pack2(acc[2] + bvv[nt], acc[3] + bvv[nt]);
          *(uint2*)(Vt + ((size_t)(b * NH + h) * NDH + nt * 16 + m) * NS + s0 +
                    st * 16 + quad * 4) = w;
        }
      }
    }
  }
}

// ---------------- Attention (R24: TB=64, cross-tile PV pipeline) -----------
// Grid: 1024 blocks = 8 xcd x 16 bh x 8 qblk; block = 128 q-rows (4 waves
// x 32 rows). K 2-buf (16KB) + V 3-buf (24KB) = 40KB LDS -> 4 blocks/CU.
__global__ __launch_bounds__(256, 4) void attn_kernel(
    const __hip_bfloat16* __restrict__ Q,   // [B,H,S,DH] pre-scaled
    const __hip_bfloat16* __restrict__ K,   // [B,H,S,DH]
    const __hip_bfloat16* __restrict__ Vt,  // [B,H,DH,S]
    float* __restrict__ out) {              // [B,S,D]
  __shared__ __align__(16) __hip_bfloat16 Kt[2][64][64];
  __shared__ __align__(16) __hip_bfloat16 Vl[3][64][64];

  const int tid = threadIdx.x;
  const int wave = tid >> 6, lane = tid & 63;
  const int m = lane & 15, quad = lane >> 4;

  const int xcd = blockIdx.x & 7;
  const int j = blockIdx.x >> 3;          // 0..127
  const int bh = xcd * 16 + (j & 15);     // same-bh blocks share an XCD (L2)
  const int qblk = j >> 4;                // 0..7
  const int qbase = qblk * 128 + wave * 32;  // 32 q-rows per wave (2 g of 16)

  const __hip_bfloat16* Qp = Q + (size_t)bh * NS * NDH;
  const __hip_bfloat16* Kp = K + (size_t)bh * NS * NDH;
  const __hip_bfloat16* Vp = Vt + (size_t)bh * NDH * NS;

  // Q as B-fragments (k32): lane holds Q[q][d = dh*32 + quad*8 + j']
  bf16x8 Bq[2][2];
#pragma unroll
  for (int g = 0; g < 2; g++)
#pragma unroll
    for (int dh = 0; dh < 2; dh++)
      Bq[g][dh] = *(const bf16x8*)(Qp + (size_t)(qbase + g * 16 + m) * NDH +
                                   dh * 32 + quad * 8);

  f32x4 accO[2][4];
  f32x4 lsum[2];
#pragma unroll
  for (int g = 0; g < 2; g++) {
    lsum[g] = (f32x4){0.f, 0.f, 0.f, 0.f};
#pragma unroll
    for (int nt = 0; nt < 4; nt++) accO[g][nt] = (f32x4){0.f, 0.f, 0.f, 0.f};
  }
  bf16x8 ones8;
#pragma unroll
  for (int i = 0; i < 8; i++) ones8[i] = (__bf16)1.0f;
  const f32x4 fzero = {0.f, 0.f, 0.f, 0.f};

  // Frag-read constants (per lane):
  const int krow = 8 * (m >> 2) + (m & 3);       // + c*32 + 4p at use site
  const int fK = (m & 3) ^ (((m >> 2) & 1) << 2);
  const int kc0 = (quad ^ fK) * 8;               // K chunk offset (elems)
  const int vbase = quad ^ (m & 7);              // V phys chunk base (^ c<<2)

  // Staging per tile: per wave 2 K-lines + 2 V-lines (8 rows x 8 chunks).
  //   K: phys = logical ^ (r&3) ^ (((r>>3)&1)<<2); V: phys = logical ^ (e&7).
#define STAGE(kb, vb, tb)                                                     \
  {                                                                           \
    _Pragma("unroll") for (int l = 0; l < 2; l++) {                           \
      const int krb = wave * 16 + l * 8;                                      \
      const int csK = (lane & 7) ^ ((lane >> 3) & 3) ^ (l << 2);              \
      gload16(Kp + (size_t)((tb) * 64 + krb + (lane >> 3)) * NDH + csK * 8,   \
              &Kt[kb][krb][0]);                                               \
      const int vrb = wave * 16 + l * 8;                                      \
      const int csV = (lane & 7) ^ (lane >> 3);                               \
      gload16(Vp + (size_t)(vrb + (lane >> 3)) * NS + (tb) * 64 + csV * 8,    \
              &Vl[vb][vrb][0]);                                               \
    }                                                                         \
  }

  // QK^T + exp for tile tb from Kt[cur_] -> PaNew (k32 A-layout).
#define QK_PHASE(cur_, PaNew)                                                 \
  {                                                                           \
    _Pragma("unroll") for (int c = 0; c < 2; c++) {                           \
      uint4 u[2];                                                             \
      _Pragma("unroll") for (int p = 0; p < 2; p++) {                         \
        const __hip_bfloat16* kr = &Kt[cur_][c * 32 + 4 * p + krow][0];       \
        bf16x8 k0 = *(const bf16x8*)(kr + kc0);                               \
        bf16x8 k1 = *(const bf16x8*)(kr + (kc0 ^ 32));                        \
        _Pragma("unroll") for (int g = 0; g < 2; g++) {                       \
          f32x4 a = mfma16(k1, Bq[g][1], mfma16(k0, Bq[g][0], fzero));        \
          unsigned w0 = pack2t(fast_exp2(a[0]), fast_exp2(a[1]));             \
          unsigned w1 = pack2t(fast_exp2(a[2]), fast_exp2(a[3]));             \
          if (p == 0) { u[g].x = w0; u[g].y = w1; }                           \
          else        { u[g].z = w0; u[g].w = w1; }                           \
        }                                                                     \
      }                                                                       \
      _Pragma("unroll") for (int g = 0; g < 2; g++)                           \
        PaNew[g][c] = __builtin_bit_cast(bf16x8, u[g]);                       \
    }                                                                         \
  }

  // denom + PV for the PREVIOUS tile: reads Vl[vbuf_], PaOld (all-reg MFMA).
#define PV_PHASE(vbuf_, PaOld)                                                \
  {                                                                           \
    _Pragma("unroll") for (int g = 0; g < 2; g++)                             \
      _Pragma("unroll") for (int c = 0; c < 2; c++)                           \
        lsum[g] = mfma16(PaOld[g][c], ones8, lsum[g]);                        \
    _Pragma("unroll") for (int nt = 0; nt < 4; nt++) {                        \
      _Pragma("unroll") for (int c = 0; c < 2; c++) {                         \
        const int off = (vbase ^ (c << 2)) << 3;                              \
        bf16x8 v = *(const bf16x8*)&Vl[vbuf_][nt * 16 + m][off];              \
        _Pragma("unroll") for (int g = 0; g < 2; g++)                         \
          accO[g][nt] = mfma16(PaOld[g][c], v, accO[g][nt]);                  \
      }                                                                       \
    }                                                                         \
  }

  STAGE(0, 0, 0);  // tile 0 -> Kt[0], Vl[0]

  bf16x8 PaA[2][2], PaB[2][2];

  // Pipeline: iter t = {barrier; STAGE(t+1); QK(t); denom+PV(t-1)}.
  // V(tile s) lives in Vl[s%3]; write (t+1)%3 vs PV-read (t-1)%3 disjoint.
  // Unrolled x2 so Pa prev/cur are statically named (no runtime reg index).
  for (int tb2 = 0; tb2 < 16; tb2 += 2) {
    // ---- even sub-iter: tb = tb2 (QK -> PaA; PV uses PaB = tile tb2-1) ----
    __syncthreads();
    STAGE(1, (tb2 + 1) % 3, tb2 + 1);   // tb2+1 <= 15 always
    QK_PHASE(0, PaA);
    if (tb2 > 0) PV_PHASE((tb2 + 2) % 3, PaB);
    // ---- odd sub-iter: tb = tb2+1 (QK -> PaB; PV uses PaA = tile tb2) ----
    __syncthreads();
    if (tb2 + 2 < 16) STAGE(0, (tb2 + 2) % 3, tb2 + 2);
    QK_PHASE(1, PaB);
    PV_PHASE(tb2 % 3, PaA);
  }
  // ---- epilogue: PV for tile 15 (V staged iter 14 into Vl[15%3=0]) ----
  PV_PHASE(0, PaB);
#undef STAGE
#undef QK_PHASE
#undef PV_PHASE

  // ---- epilogue: O[q][e]/l[q]; q = quad*4+r, e = nt*16+m ----
  const int b = bh >> 4, h = bh & (NH - 1);
#pragma unroll
  for (int g = 0; g < 2; g++) {
#pragma unroll
    for (int r = 0; r < 4; r++) {
      float inv = 1.0f / lsum[g][r];
      int srow = qbase + g * 16 + quad * 4 + r;
      float* op = out + (size_t)(b * NS + srow) * ND + h * NDH;
#pragma unroll
      for (int nt = 0; nt < 4; nt++) op[nt * 16 + m] = accO[g][nt][r] * inv;
    }
  }
}

extern "C" void kernel_launch(void* const* d_in, const int* in_sizes, int n_in,
                              void* d_out, int out_size, void* d_ws, size_t ws_size,
                              hipStream_t stream) {
  const float* x  = (const float*)d_in[0];
  const float* Wq = (const float*)d_in[1];
  const float* bq = (const float*)d_in[2];
  const float* Wk = (const float*)d_in[3];
  const float* bk = (const float*)d_in[4];
  const float* Wv = (const float*)d_in[5];
  const float* bv = (const float*)d_in[6];
  float* out = (float*)d_out;

  const size_t elems = (size_t)NB * NH * NS * NDH;
  __hip_bfloat16* Qw = (__hip_bfloat16*)d_ws;
  __hip_bfloat16* Kw = Qw + elems;
  __hip_bfloat16* Vw = Kw + elems;

  // R13 qkv: 512 blocks, 256 rows each (measured in the 140.2 config)
  qkv_proj_kernel<<<512, 256, 0, stream>>>(x, Wq, bq, Wk, bk, Wv, bv, Qw, Kw, Vw);
  // R24 attn: 8 xcd x 16 bh x 8 qblk; 128 q-rows/block; 4 blocks/CU
  attn_kernel<<<1024, 256, 0, stream>>>(Qw, Kw, Vw, out);
}

// Round 13
// 145.812 us; speedup vs baseline: 1.1934x; 1.0520x over previous
//
#include <hip/hip_runtime.h>
#include <hip/hip_bf16.h>

// MHA: B=8, S=1024, D=1024, H=16, DH=64.
// R26: [qkv] R13 (measured-good). [attn] = R20 (TB=64, 41.4us verified)
// with ONLY the sync structure changed (T4 counted-vmcnt, m201 template):
//  - K/V triple-buffered (48KB LDS, 3 blk/CU), staging 2 tiles ahead,
//  - __syncthreads() -> asm "s_waitcnt vmcnt(4); s_barrier" (memory clobber):
//    waits tile t's 4 loads only; tile t+1's 4 stay in flight ACROSS the
//    barrier. Never drains to 0 in-loop (vmcnt(0) only at t=15 tail).
//  - zero new register state (R24 lesson: deferred-PV spilled -> WRITE_SIZE
//    32->86MB, attn 58us. WRITE_SIZE==output-size is the spill detector).
// Buffer safety: write (t+2)%3 / read t%3 / in-flight (t+1)%3 disjoint;
// one barrier/tile suffices (STAGE(t+3) only happens after all waves passed
// barrier t+1, i.e. finished compute(t)).

constexpr int NB = 8, NS = 1024, ND = 1024, NH = 16, NDH = 64;

typedef __bf16 bf16x8 __attribute__((ext_vector_type(8)));
typedef float f32x4 __attribute__((ext_vector_type(4)));

__device__ __forceinline__ f32x4 mfma16(bf16x8 a, bf16x8 b, f32x4 c) {
  return __builtin_amdgcn_mfma_f32_16x16x32_bf16(a, b, c, 0, 0, 0);
}

__device__ __forceinline__ float fast_exp2(float x) {
#if __has_builtin(__builtin_amdgcn_exp2f)
  return __builtin_amdgcn_exp2f(x);   // raw v_exp_f32
#else
  return __builtin_exp2f(x);
#endif
}

// RNE-ish pack (round-half-up) — used in proj where cost is negligible.
__device__ __forceinline__ unsigned pack2(float lo, float hi) {
  unsigned uh = __builtin_bit_cast(unsigned, hi) + 0x8000u;
  unsigned ul = __builtin_bit_cast(unsigned, lo) + 0x8000u;
  return __builtin_amdgcn_perm(uh, ul, 0x07060302u);
}

// Truncation pack — 1 VALU; used for P (bias cancels num/den).
__device__ __forceinline__ unsigned pack2t(float lo, float hi) {
  return __builtin_amdgcn_perm(__builtin_bit_cast(unsigned, hi),
                               __builtin_bit_cast(unsigned, lo), 0x07060302u);
}

__device__ __forceinline__ bf16x8 cvt2bf8(float4 lo, float4 hi) {
  bf16x8 r;
  r[0] = (__bf16)lo.x; r[1] = (__bf16)lo.y; r[2] = (__bf16)lo.z; r[3] = (__bf16)lo.w;
  r[4] = (__bf16)hi.x; r[5] = (__bf16)hi.y; r[6] = (__bf16)hi.z; r[7] = (__bf16)hi.w;
  return r;
}

__device__ __forceinline__ void gload16(const __hip_bfloat16* g, __hip_bfloat16* l) {
  __builtin_amdgcn_global_load_lds(
      (const __attribute__((address_space(1))) void*)g,
      (__attribute__((address_space(3))) void*)l, 16, 0, 0);
}

// ---------------- QKV projection (R13 version — measured-good) ----------
__global__ __launch_bounds__(256) void qkv_proj_kernel(
    const float* __restrict__ x,
    const float* __restrict__ Wq, const float* __restrict__ bq,
    const float* __restrict__ Wk, const float* __restrict__ bk,
    const float* __restrict__ Wv, const float* __restrict__ bv,
    __hip_bfloat16* __restrict__ Qo, __hip_bfloat16* __restrict__ Ko,
    __hip_bfloat16* __restrict__ Vt) {
  __shared__ __align__(16) __hip_bfloat16 Wlds[3][NDH][72];
  const int tid = threadIdx.x;
  const int wave = tid >> 6, lane = tid & 63;
  const int m = lane & 15, quad = lane >> 4;
  const int h = blockIdx.x & (NH - 1);
  const int sblk = blockIdx.x >> 4;

  const float* Ws[3] = {Wq + h * 4096, Wk + h * 4096, Wv + h * 4096};
#pragma unroll
  for (int mt = 0; mt < 3; mt++) {
#pragma unroll
    for (int p = 0; p < 4; p++) {
      int idx = (p * 256 + tid) * 4;
      float4 v = *(const float4*)(Ws[mt] + idx);
      uint2 w;
      w.x = pack2(v.x, v.y);
      w.y = pack2(v.z, v.w);
      *(uint2*)&Wlds[mt][idx >> 6][idx & 63] = w;
    }
  }
  __syncthreads();

  float bq4[4][4], bk4[4][4], bvv[4];
#pragma unroll
  for (int nt = 0; nt < 4; nt++) {
    float4 a = *(const float4*)(bq + h * 64 + nt * 16 + quad * 4);
    float4 c = *(const float4*)(bk + h * 64 + nt * 16 + quad * 4);
    bq4[nt][0] = a.x; bq4[nt][1] = a.y; bq4[nt][2] = a.z; bq4[nt][3] = a.w;
    bk4[nt][0] = c.x; bk4[nt][1] = c.y; bk4[nt][2] = c.z; bk4[nt][3] = c.w;
    bvv[nt] = bv[h * 64 + nt * 16 + m];
  }

  const int rowbase = sblk * 256 + wave * 64;
  bf16x8 Xf[4][2];
#pragma unroll
  for (int st = 0; st < 4; st++) {
    const float* xp = x + (size_t)(rowbase + st * 16 + m) * ND + h * NDH + quad * 8;
#pragma unroll
    for (int c = 0; c < 2; c++) {
      float4 lo = *(const float4*)(xp + c * 32);
      float4 hi = *(const float4*)(xp + c * 32 + 4);
      Xf[st][c] = cvt2bf8(lo, hi);
    }
  }

  const int b = rowbase >> 10;
  const int s0 = rowbase & 1023;
  const float qscale = 0.18033688011112042f;  // log2(e)/sqrt(64)

#pragma unroll
  for (int mt = 0; mt < 3; mt++) {
#pragma unroll
    for (int nt = 0; nt < 4; nt++) {
      bf16x8 w0 = *(const bf16x8*)&Wlds[mt][nt * 16 + m][quad * 8];
      bf16x8 w1 = *(const bf16x8*)&Wlds[mt][nt * 16 + m][32 + quad * 8];
#pragma unroll
      for (int st = 0; st < 4; st++) {
        f32x4 acc = {0.f, 0.f, 0.f, 0.f};
        if (mt < 2) {
          acc = mfma16(w0, Xf[st][0], acc);
          acc = mfma16(w1, Xf[st][1], acc);
          const int srow = s0 + st * 16 + m;
          uint2 w;
          if (mt == 0) {
            w.x = pack2((acc[0] + bq4[nt][0]) * qscale, (acc[1] + bq4[nt][1]) * qscale);
            w.y = pack2((acc[2] + bq4[nt][2]) * qscale, (acc[3] + bq4[nt][3]) * qscale);
            *(uint2*)(Qo + ((size_t)(b * NH + h) * NS + srow) * NDH +
                      nt * 16 + quad * 4) = w;
          } else {
            w.x = pack2(acc[0] + bk4[nt][0], acc[1] + bk4[nt][1]);
            w.y = pack2(acc[2] + bk4[nt][2], acc[3] + bk4[nt][3]);
            *(uint2*)(Ko + ((size_t)(b * NH + h) * NS + srow) * NDH +
                      nt * 16 + quad * 4) = w;
          }
        } else {
          acc = mfma16(Xf[st][0], w0, acc);
          acc = mfma16(Xf[st][1], w1, acc);
          uint2 w;
          w.x = pack2(acc[0] + bvv[nt], acc[1] + bvv[nt]);
          w.y = pack2(acc[2] + bvv[nt], acc[3] + bvv[nt]);
          *(uint2*)(Vt + ((size_t)(b * NH + h) * NDH + nt * 16 + m) * NS + s0 +
                    st * 16 + quad * 4) = w;
        }
      }
    }
  }
}

// ---------------- Attention (R26: TB=64, counted-vmcnt pipeline) -----------
// Grid: 1024 blocks = 8 xcd x 16 bh x 8 qblk; block = 128 q-rows (4 waves
// x 32 rows). K/V triple-buffered 64x64 tiles: 48KB LDS -> 3 blocks/CU.
__global__ __launch_bounds__(256, 3) void attn_kernel(
    const __hip_bfloat16* __restrict__ Q,   // [B,H,S,DH] pre-scaled
    const __hip_bfloat16* __restrict__ K,   // [B,H,S,DH]
    const __hip_bfloat16* __restrict__ Vt,  // [B,H,DH,S]
    float* __restrict__ out) {              // [B,S,D]
  __shared__ __align__(16) __hip_bfloat16 Kt[3][64][64];
  __shared__ __align__(16) __hip_bfloat16 Vl[3][64][64];

  const int tid = threadIdx.x;
  const int wave = tid >> 6, lane = tid & 63;
  const int m = lane & 15, quad = lane >> 4;

  const int xcd = blockIdx.x & 7;
  const int j = blockIdx.x >> 3;          // 0..127
  const int bh = xcd * 16 + (j & 15);     // same-bh blocks share an XCD (L2)
  const int qblk = j >> 4;                // 0..7
  const int qbase = qblk * 128 + wave * 32;  // 32 q-rows per wave (2 g of 16)

  const __hip_bfloat16* Qp = Q + (size_t)bh * NS * NDH;
  const __hip_bfloat16* Kp = K + (size_t)bh * NS * NDH;
  const __hip_bfloat16* Vp = Vt + (size_t)bh * NDH * NS;

  // Q as B-fragments (k32): lane holds Q[q][d = dh*32 + quad*8 + j']
  bf16x8 Bq[2][2];
#pragma unroll
  for (int g = 0; g < 2; g++)
#pragma unroll
    for (int dh = 0; dh < 2; dh++)
      Bq[g][dh] = *(const bf16x8*)(Qp + (size_t)(qbase + g * 16 + m) * NDH +
                                   dh * 32 + quad * 8);

  f32x4 accO[2][4];
  f32x4 lsum[2];
#pragma unroll
  for (int g = 0; g < 2; g++) {
    lsum[g] = (f32x4){0.f, 0.f, 0.f, 0.f};
#pragma unroll
    for (int nt = 0; nt < 4; nt++) accO[g][nt] = (f32x4){0.f, 0.f, 0.f, 0.f};
  }
  bf16x8 ones8;
#pragma unroll
  for (int i = 0; i < 8; i++) ones8[i] = (__bf16)1.0f;
  const f32x4 fzero = {0.f, 0.f, 0.f, 0.f};

  // Frag-read constants (per lane):
  const int krow = 8 * (m >> 2) + (m & 3);       // + c*32 + 4p at use site
  const int fK = (m & 3) ^ (((m >> 2) & 1) << 2);
  const int kc0 = (quad ^ fK) * 8;               // K chunk offset (elems)
  const int vbase = quad ^ (m & 7);              // V phys chunk base (^ c<<2)

  // Staging per tile: per wave 2 K-lines + 2 V-lines (8 rows x 8 chunks).
  //   K: phys = logical ^ (r&3) ^ (((r>>3)&1)<<2); V: phys = logical ^ (e&7).
  // 4 gload_lds per wave per STAGE — the vmcnt unit of account.
#define STAGE(buf, tb)                                                        \
  {                                                                           \
    _Pragma("unroll") for (int l = 0; l < 2; l++) {                           \
      const int krb = wave * 16 + l * 8;                                      \
      const int csK = (lane & 7) ^ ((lane >> 3) & 3) ^ (l << 2);              \
      gload16(Kp + (size_t)((tb) * 64 + krb + (lane >> 3)) * NDH + csK * 8,   \
              &Kt[buf][krb][0]);                                              \
      const int vrb = wave * 16 + l * 8;                                      \
      const int csV = (lane & 7) ^ (lane >> 3);                               \
      gload16(Vp + (size_t)(vrb + (lane >> 3)) * NS + (tb) * 64 + csV * 8,    \
              &Vl[buf][vrb][0]);                                              \
    }                                                                         \
  }

  // Counted-vmcnt barrier: wait until <= N of this wave's VMEM ops remain,
  // then block-sync. Memory clobber pins all loads/stores on both sides.
#define SYNC(N) asm volatile("s_waitcnt vmcnt(" #N ")\n\ts_barrier" ::: "memory")

  STAGE(0, 0);  // tile 0 -> buf 0
  STAGE(1, 1);  // tile 1 -> buf 1

  for (int tb = 0; tb < 16; tb++) {
    const int cur = tb % 3;
    if (tb < 14) {
      SYNC(4);                     // tile tb landed; tile tb+1 stays in flight
      STAGE((tb + 2) % 3, tb + 2); // prefetch 2 ahead
    } else if (tb == 14) {
      SYNC(4);                     // tile 14 landed; tile 15 in flight
    } else {
      SYNC(0);                     // tail: drain tile 15
    }

    // ---- phase-split QK^T + exp: P lands in k32 A-layout ----
    bf16x8 Pa[2][2];  // [g][c]: lane holds P[q][t = c*32 + 8*quad + j]
#pragma unroll
    for (int c = 0; c < 2; c++) {
      uint4 u[2];
#pragma unroll
      for (int p = 0; p < 2; p++) {
        const __hip_bfloat16* kr = &Kt[cur][c * 32 + 4 * p + krow][0];
        bf16x8 k0 = *(const bf16x8*)(kr + kc0);
        bf16x8 k1 = *(const bf16x8*)(kr + (kc0 ^ 32));
#pragma unroll
        for (int g = 0; g < 2; g++) {
          f32x4 a = mfma16(k1, Bq[g][1], mfma16(k0, Bq[g][0], fzero));
          unsigned w0 = pack2t(fast_exp2(a[0]), fast_exp2(a[1]));
          unsigned w1 = pack2t(fast_exp2(a[2]), fast_exp2(a[3]));
          if (p == 0) { u[g].x = w0; u[g].y = w1; }
          else        { u[g].z = w0; u[g].w = w1; }
        }
      }
#pragma unroll
      for (int g = 0; g < 2; g++) Pa[g][c] = __builtin_bit_cast(bf16x8, u[g]);
    }
    // ---- pure-MFMA cluster: denom + PV (T5 retained, baseline parity) ----
    __builtin_amdgcn_s_setprio(1);
#pragma unroll
    for (int g = 0; g < 2; g++)
#pragma unroll
      for (int c = 0; c < 2; c++) lsum[g] = mfma16(Pa[g][c], ones8, lsum[g]);
#pragma unroll
    for (int nt = 0; nt < 4; nt++) {
#pragma unroll
      for (int c = 0; c < 2; c++) {
        const int off = (vbase ^ (c << 2)) << 3;
        bf16x8 v = *(const bf16x8*)&Vl[cur][nt * 16 + m][off];
#pragma unroll
        for (int g = 0; g < 2; g++)
          accO[g][nt] = mfma16(Pa[g][c], v, accO[g][nt]);
      }
    }
    __builtin_amdgcn_s_setprio(0);
  }
#undef STAGE
#undef SYNC

  // ---- epilogue: O[q][e]/l[q]; q = quad*4+r, e = nt*16+m ----
  const int b = bh >> 4, h = bh & (NH - 1);
#pragma unroll
  for (int g = 0; g < 2; g++) {
#pragma unroll
    for (int r = 0; r < 4; r++) {
      float inv = 1.0f / lsum[g][r];
      int srow = qbase + g * 16 + quad * 4 + r;
      float* op = out + (size_t)(b * NS + srow) * ND + h * NDH;
#pragma unroll
      for (int nt = 0; nt < 4; nt++) op[nt * 16 + m] = accO[g][nt][r] * inv;
    }
  }
}

extern "C" void kernel_launch(void* const* d_in, const int* in_sizes, int n_in,
                              void* d_out, int out_size, void* d_ws, size_t ws_size,
                              hipStream_t stream) {
  const float* x  = (const float*)d_in[0];
  const float* Wq = (const float*)d_in[1];
  const float* bq = (const float*)d_in[2];
  const float* Wk = (const float*)d_in[3];
  const float* bk = (const float*)d_in[4];
  const float* Wv = (const float*)d_in[5];
  const float* bv = (const float*)d_in[6];
  float* out = (float*)d_out;

  const size_t elems = (size_t)NB * NH * NS * NDH;
  __hip_bfloat16* Qw = (__hip_bfloat16*)d_ws;
  __hip_bfloat16* Kw = Qw + elems;
  __hip_bfloat16* Vw = Kw + elems;

  // R13 qkv: 512 blocks, 256 rows each (measured in the 140.2 config)
  qkv_proj_kernel<<<512, 256, 0, stream>>>(x, Wq, bq, Wk, bk, Wv, bv, Qw, Kw, Vw);
  // R26 attn: 8 xcd x 16 bh x 8 qblk; 128 q-rows/block; 3 blocks/CU
  attn_kernel<<<1024, 256, 0, stream>>>(Qw, Kw, Vw, out);
}

// Round 15
// 141.490 us; speedup vs baseline: 1.2299x; 1.0305x over previous
//
#include <hip/hip_runtime.h>
#include <hip/hip_bf16.h>

// MHA: B=8, S=1024, D=1024, H=16, DH=64.
// R30 == R28 resubmitted (infra timeout; never measured).
// [qkv] R13 (measured-good). [attn] = R20 exact geometry (TB=64,
// 2-buf 32KB LDS, 4 blk/CU, plain __syncthreads -- best measured, 41.4us)
// with ONE change: intra-tile software pipeline by pure code motion:
//   QK+exp(c0) -> QK-MFMA-only(c1, raw f32 kept) -> denom+PV(c0) [MFMA]
//   -> exp+pack(c1) [VALU, independent of PV(c0)] -> denom+PV(c1).
// Zero sync/LDS/layout changes; setprio dropped (null twice; no pure-MFMA
// cluster remains). +16 VGPR for the held c1 raw scores; spill watched via
// WRITE_SIZE (R24 lesson: spill shows as WRITE_SIZE >> 32MB output).
// Evidence trail: counted-vmcnt (R26) regressed 41.4->48.1 (occ 4->3,
// FETCH +15MB) => barrier drain was NOT the stall; dual-idle is per-wave
// dependency chains. This reorder feeds the scheduler independent
// MFMA (PV c0) + VALU (exp c1) work in one region.

constexpr int NB = 8, NS = 1024, ND = 1024, NH = 16, NDH = 64;

typedef __bf16 bf16x8 __attribute__((ext_vector_type(8)));
typedef float f32x4 __attribute__((ext_vector_type(4)));

__device__ __forceinline__ f32x4 mfma16(bf16x8 a, bf16x8 b, f32x4 c) {
  return __builtin_amdgcn_mfma_f32_16x16x32_bf16(a, b, c, 0, 0, 0);
}

__device__ __forceinline__ float fast_exp2(float x) {
#if __has_builtin(__builtin_amdgcn_exp2f)
  return __builtin_amdgcn_exp2f(x);   // raw v_exp_f32
#else
  return __builtin_exp2f(x);
#endif
}

// RNE-ish pack (round-half-up) — used in proj where cost is negligible.
__device__ __forceinline__ unsigned pack2(float lo, float hi) {
  unsigned uh = __builtin_bit_cast(unsigned, hi) + 0x8000u;
  unsigned ul = __builtin_bit_cast(unsigned, lo) + 0x8000u;
  return __builtin_amdgcn_perm(uh, ul, 0x07060302u);
}

// Truncation pack — 1 VALU; used for P (bias cancels num/den).
__device__ __forceinline__ unsigned pack2t(float lo, float hi) {
  return __builtin_amdgcn_perm(__builtin_bit_cast(unsigned, hi),
                               __builtin_bit_cast(unsigned, lo), 0x07060302u);
}

__device__ __forceinline__ bf16x8 cvt2bf8(float4 lo, float4 hi) {
  bf16x8 r;
  r[0] = (__bf16)lo.x; r[1] = (__bf16)lo.y; r[2] = (__bf16)lo.z; r[3] = (__bf16)lo.w;
  r[4] = (__bf16)hi.x; r[5] = (__bf16)hi.y; r[6] = (__bf16)hi.z; r[7] = (__bf16)hi.w;
  return r;
}

__device__ __forceinline__ void gload16(const __hip_bfloat16* g, __hip_bfloat16* l) {
  __builtin_amdgcn_global_load_lds(
      (const __attribute__((address_space(1))) void*)g,
      (__attribute__((address_space(3))) void*)l, 16, 0, 0);
}

// ---------------- QKV projection (R13 version — measured-good) ----------
__global__ __launch_bounds__(256) void qkv_proj_kernel(
    const float* __restrict__ x,
    const float* __restrict__ Wq, const float* __restrict__ bq,
    const float* __restrict__ Wk, const float* __restrict__ bk,
    const float* __restrict__ Wv, const float* __restrict__ bv,
    __hip_bfloat16* __restrict__ Qo, __hip_bfloat16* __restrict__ Ko,
    __hip_bfloat16* __restrict__ Vt) {
  __shared__ __align__(16) __hip_bfloat16 Wlds[3][NDH][72];
  const int tid = threadIdx.x;
  const int wave = tid >> 6, lane = tid & 63;
  const int m = lane & 15, quad = lane >> 4;
  const int h = blockIdx.x & (NH - 1);
  const int sblk = blockIdx.x >> 4;

  const float* Ws[3] = {Wq + h * 4096, Wk + h * 4096, Wv + h * 4096};
#pragma unroll
  for (int mt = 0; mt < 3; mt++) {
#pragma unroll
    for (int p = 0; p < 4; p++) {
      int idx = (p * 256 + tid) * 4;
      float4 v = *(const float4*)(Ws[mt] + idx);
      uint2 w;
      w.x = pack2(v.x, v.y);
      w.y = pack2(v.z, v.w);
      *(uint2*)&Wlds[mt][idx >> 6][idx & 63] = w;
    }
  }
  __syncthreads();

  float bq4[4][4], bk4[4][4], bvv[4];
#pragma unroll
  for (int nt = 0; nt < 4; nt++) {
    float4 a = *(const float4*)(bq + h * 64 + nt * 16 + quad * 4);
    float4 c = *(const float4*)(bk + h * 64 + nt * 16 + quad * 4);
    bq4[nt][0] = a.x; bq4[nt][1] = a.y; bq4[nt][2] = a.z; bq4[nt][3] = a.w;
    bk4[nt][0] = c.x; bk4[nt][1] = c.y; bk4[nt][2] = c.z; bk4[nt][3] = c.w;
    bvv[nt] = bv[h * 64 + nt * 16 + m];
  }

  const int rowbase = sblk * 256 + wave * 64;
  bf16x8 Xf[4][2];
#pragma unroll
  for (int st = 0; st < 4; st++) {
    const float* xp = x + (size_t)(rowbase + st * 16 + m) * ND + h * NDH + quad * 8;
#pragma unroll
    for (int c = 0; c < 2; c++) {
      float4 lo = *(const float4*)(xp + c * 32);
      float4 hi = *(const float4*)(xp + c * 32 + 4);
      Xf[st][c] = cvt2bf8(lo, hi);
    }
  }

  const int b = rowbase >> 10;
  const int s0 = rowbase & 1023;
  const float qscale = 0.18033688011112042f;  // log2(e)/sqrt(64)

#pragma unroll
  for (int mt = 0; mt < 3; mt++) {
#pragma unroll
    for (int nt = 0; nt < 4; nt++) {
      bf16x8 w0 = *(const bf16x8*)&Wlds[mt][nt * 16 + m][quad * 8];
      bf16x8 w1 = *(const bf16x8*)&Wlds[mt][nt * 16 + m][32 + quad * 8];
#pragma unroll
      for (int st = 0; st < 4; st++) {
        f32x4 acc = {0.f, 0.f, 0.f, 0.f};
        if (mt < 2) {
          acc = mfma16(w0, Xf[st][0], acc);
          acc = mfma16(w1, Xf[st][1], acc);
          const int srow = s0 + st * 16 + m;
          uint2 w;
          if (mt == 0) {
            w.x = pack2((acc[0] + bq4[nt][0]) * qscale, (acc[1] + bq4[nt][1]) * qscale);
            w.y = pack2((acc[2] + bq4[nt][2]) * qscale, (acc[3] + bq4[nt][3]) * qscale);
            *(uint2*)(Qo + ((size_t)(b * NH + h) * NS + srow) * NDH +
                      nt * 16 + quad * 4) = w;
          } else {
            w.x = pack2(acc[0] + bk4[nt][0], acc[1] + bk4[nt][1]);
            w.y = pack2(acc[2] + bk4[nt][2], acc[3] + bk4[nt][3]);
            *(uint2*)(Ko + ((size_t)(b * NH + h) * NS + srow) * NDH +
                      nt * 16 + quad * 4) = w;
          }
        } else {
          acc = mfma16(Xf[st][0], w0, acc);
          acc = mfma16(Xf[st][1], w1, acc);
          uint2 w;
          w.x = pack2(acc[0] + bvv[nt], acc[1] + bvv[nt]);
          w.y = pack2(acc[2] + bvv[nt], acc[3] + bvv[nt]);
          *(uint2*)(Vt + ((size_t)(b * NH + h) * NDH + nt * 16 + m) * NS + s0 +
                    st * 16 + quad * 4) = w;
        }
      }
    }
  }
}

// ---------------- Attention (R28: R20 geometry + intra-tile pipeline) ------
// Grid: 1024 blocks = 8 xcd x 16 bh x 8 qblk; block = 128 q-rows (4 waves
// x 32 rows). K/V tiles 64-wide, double-buffered: 2*(8KB+8KB) = 32KB LDS.
__global__ __launch_bounds__(256, 4) void attn_kernel(
    const __hip_bfloat16* __restrict__ Q,   // [B,H,S,DH] pre-scaled
    const __hip_bfloat16* __restrict__ K,   // [B,H,S,DH]
    const __hip_bfloat16* __restrict__ Vt,  // [B,H,DH,S]
    float* __restrict__ out) {              // [B,S,D]
  __shared__ __align__(16) __hip_bfloat16 Kt[2][64][64];
  __shared__ __align__(16) __hip_bfloat16 Vl[2][64][64];

  const int tid = threadIdx.x;
  const int wave = tid >> 6, lane = tid & 63;
  const int m = lane & 15, quad = lane >> 4;

  const int xcd = blockIdx.x & 7;
  const int j = blockIdx.x >> 3;          // 0..127
  const int bh = xcd * 16 + (j & 15);     // same-bh blocks share an XCD (L2)
  const int qblk = j >> 4;                // 0..7
  const int qbase = qblk * 128 + wave * 32;  // 32 q-rows per wave (2 g of 16)

  const __hip_bfloat16* Qp = Q + (size_t)bh * NS * NDH;
  const __hip_bfloat16* Kp = K + (size_t)bh * NS * NDH;
  const __hip_bfloat16* Vp = Vt + (size_t)bh * NDH * NS;

  // Q as B-fragments (k32): lane holds Q[q][d = dh*32 + quad*8 + j']
  bf16x8 Bq[2][2];
#pragma unroll
  for (int g = 0; g < 2; g++)
#pragma unroll
    for (int dh = 0; dh < 2; dh++)
      Bq[g][dh] = *(const bf16x8*)(Qp + (size_t)(qbase + g * 16 + m) * NDH +
                                   dh * 32 + quad * 8);

  f32x4 accO[2][4];
  f32x4 lsum[2];
#pragma unroll
  for (int g = 0; g < 2; g++) {
    lsum[g] = (f32x4){0.f, 0.f, 0.f, 0.f};
#pragma unroll
    for (int nt = 0; nt < 4; nt++) accO[g][nt] = (f32x4){0.f, 0.f, 0.f, 0.f};
  }
  bf16x8 ones8;
#pragma unroll
  for (int i = 0; i < 8; i++) ones8[i] = (__bf16)1.0f;
  const f32x4 fzero = {0.f, 0.f, 0.f, 0.f};

  // Frag-read constants (per lane):
  const int krow = 8 * (m >> 2) + (m & 3);       // + c*32 + 4p at use site
  const int fK = (m & 3) ^ (((m >> 2) & 1) << 2);
  const int kc0 = (quad ^ fK) * 8;               // K chunk offset (elems)
  const int vbase = quad ^ (m & 7);              // V phys chunk base (^ c<<2)

  // Staging per tile (64x64 K + 64x64 V): per wave 2 K-lines + 2 V-lines.
  //   K: phys = logical ^ (r&3) ^ (((r>>3)&1)<<2); V: phys = logical ^ (e&7).
#define STAGE(buf, tb)                                                        \
  {                                                                           \
    _Pragma("unroll") for (int l = 0; l < 2; l++) {                           \
      const int krb = wave * 16 + l * 8;                                      \
      const int csK = (lane & 7) ^ ((lane >> 3) & 3) ^ (l << 2);              \
      gload16(Kp + (size_t)((tb) * 64 + krb + (lane >> 3)) * NDH + csK * 8,   \
              &Kt[buf][krb][0]);                                              \
      const int vrb = wave * 16 + l * 8;                                      \
      const int csV = (lane & 7) ^ (lane >> 3);                               \
      gload16(Vp + (size_t)(vrb + (lane >> 3)) * NS + (tb) * 64 + csV * 8,    \
              &Vl[buf][vrb][0]);                                              \
    }                                                                         \
  }

  STAGE(0, 0);

  for (int tb = 0; tb < 16; tb++) {
    const int cur = tb & 1;
    __syncthreads();  // own staging drained (vmcnt 0) + block synced
    if (tb + 1 < 16) STAGE(cur ^ 1, tb + 1);  // prefetch overlaps compute

    // ================= intra-tile pipeline =================
    // (1) QK + exp + pack for c=0 -> Pa0
    bf16x8 Pa0[2], Pa1[2];
    {
      uint4 u[2];
#pragma unroll
      for (int p = 0; p < 2; p++) {
        const __hip_bfloat16* kr = &Kt[cur][4 * p + krow][0];
        bf16x8 k0 = *(const bf16x8*)(kr + kc0);
        bf16x8 k1 = *(const bf16x8*)(kr + (kc0 ^ 32));
#pragma unroll
        for (int g = 0; g < 2; g++) {
          f32x4 a = mfma16(k1, Bq[g][1], mfma16(k0, Bq[g][0], fzero));
          unsigned w0 = pack2t(fast_exp2(a[0]), fast_exp2(a[1]));
          unsigned w1 = pack2t(fast_exp2(a[2]), fast_exp2(a[3]));
          if (p == 0) { u[g].x = w0; u[g].y = w1; }
          else        { u[g].z = w0; u[g].w = w1; }
        }
      }
#pragma unroll
      for (int g = 0; g < 2; g++) Pa0[g] = __builtin_bit_cast(bf16x8, u[g]);
    }

    // (2) QK MFMAs only for c=1 — raw f32 scores held (+16 VGPR)
    f32x4 a1[2][2];  // [p][g]
#pragma unroll
    for (int p = 0; p < 2; p++) {
      const __hip_bfloat16* kr = &Kt[cur][32 + 4 * p + krow][0];
      bf16x8 k0 = *(const bf16x8*)(kr + kc0);
      bf16x8 k1 = *(const bf16x8*)(kr + (kc0 ^ 32));
#pragma unroll
      for (int g = 0; g < 2; g++)
        a1[p][g] = mfma16(k1, Bq[g][1], mfma16(k0, Bq[g][0], fzero));
    }

    // (3) denom + PV for c=0 (MFMA pipe; independent of exp(c1))
#pragma unroll
    for (int g = 0; g < 2; g++) lsum[g] = mfma16(Pa0[g], ones8, lsum[g]);
#pragma unroll
    for (int nt = 0; nt < 4; nt++) {
      const int off0 = vbase << 3;
      bf16x8 v = *(const bf16x8*)&Vl[cur][nt * 16 + m][off0];
#pragma unroll
      for (int g = 0; g < 2; g++)
        accO[g][nt] = mfma16(Pa0[g], v, accO[g][nt]);
    }

    // (4) exp + pack for c=1 (VALU pipe; scheduler overlaps with (3))
    {
      uint4 u[2];
#pragma unroll
      for (int p = 0; p < 2; p++)
#pragma unroll
        for (int g = 0; g < 2; g++) {
          unsigned w0 = pack2t(fast_exp2(a1[p][g][0]), fast_exp2(a1[p][g][1]));
          unsigned w1 = pack2t(fast_exp2(a1[p][g][2]), fast_exp2(a1[p][g][3]));
          if (p == 0) { u[g].x = w0; u[g].y = w1; }
          else        { u[g].z = w0; u[g].w = w1; }
        }
#pragma unroll
      for (int g = 0; g < 2; g++) Pa1[g] = __builtin_bit_cast(bf16x8, u[g]);
    }

    // (5) denom + PV for c=1
#pragma unroll
    for (int g = 0; g < 2; g++) lsum[g] = mfma16(Pa1[g], ones8, lsum[g]);
#pragma unroll
    for (int nt = 0; nt < 4; nt++) {
      const int off1 = (vbase ^ 4) << 3;
      bf16x8 v = *(const bf16x8*)&Vl[cur][nt * 16 + m][off1];
#pragma unroll
      for (int g = 0; g < 2; g++)
        accO[g][nt] = mfma16(Pa1[g], v, accO[g][nt]);
    }
  }
#undef STAGE

  // ---- epilogue: O[q][e]/l[q]; q = quad*4+r, e = nt*16+m ----
  const int b = bh >> 4, h = bh & (NH - 1);
#pragma unroll
  for (int g = 0; g < 2; g++) {
#pragma unroll
    for (int r = 0; r < 4; r++) {
      float inv = 1.0f / lsum[g][r];
      int srow = qbase + g * 16 + quad * 4 + r;
      float* op = out + (size_t)(b * NS + srow) * ND + h * NDH;
#pragma unroll
      for (int nt = 0; nt < 4; nt++) op[nt * 16 + m] = accO[g][nt][r] * inv;
    }
  }
}

extern "C" void kernel_launch(void* const* d_in, const int* in_sizes, int n_in,
                              void* d_out, int out_size, void* d_ws, size_t ws_size,
                              hipStream_t stream) {
  const float* x  = (const float*)d_in[0];
  const float* Wq = (const float*)d_in[1];
  const float* bq = (const float*)d_in[2];
  const float* Wk = (const float*)d_in[3];
  const float* bk = (const float*)d_in[4];
  const float* Wv = (const float*)d_in[5];
  const float* bv = (const float*)d_in[6];
  float* out = (float*)d_out;

  const size_t elems = (size_t)NB * NH * NS * NDH;
  __hip_bfloat16* Qw = (__hip_bfloat16*)d_ws;
  __hip_bfloat16* Kw = Qw + elems;
  __hip_bfloat16* Vw = Kw + elems;

  // R13 qkv: 512 blocks, 256 rows each (measured in the 140.2 config)
  qkv_proj_kernel<<<512, 256, 0, stream>>>(x, Wq, bq, Wk, bk, Wv, bv, Qw, Kw, Vw);
  // R28 attn: 8 xcd x 16 bh x 8 qblk; 128 q-rows/block; 4 blocks/CU
  attn_kernel<<<1024, 256, 0, stream>>>(Qw, Kw, Vw, out);
}